// Round 1
// baseline (23547.859 us; speedup 1.0000x reference)
//
#include <hip/hip_runtime.h>

#define DEV __device__ __forceinline__

typedef short s4v __attribute__((ext_vector_type(4)));
typedef float f4v __attribute__((ext_vector_type(4)));

DEV short f2bf(float f) {
  unsigned u = __float_as_uint(f);
  u += 0x7FFFu + ((u >> 16) & 1u);
  return (short)(u >> 16);
}
DEV float bf2f(short s) {
  return __uint_as_float(((unsigned)(unsigned short)s) << 16);
}

// ---------------- generic bf16 MFMA GEMM ----------------
// C[M,N] = epilogue(A[M,K] @ B), A fp32 or bf16; B fp32, [K,N] (NN) or [N,K] (BT).
// flags: 1=+bias[col], 2=exact GELU, 4=accumulate into C (fp32 C only), 8=bf16 output
// z-batching: offsets = (z/zH)*z?b + (z%zH)*z?h  (element offsets)
constexpr int BM = 128, BN = 128, BK = 32;

template<bool BT, bool A16>
__global__ __launch_bounds__(256) void gemm_k(
    const void* __restrict__ Av, const float* __restrict__ B, void* __restrict__ Cv,
    const float* __restrict__ bias,
    int M, int N, int K, int lda, int ldb, int ldc, int flags, int zH,
    long zAb, long zAh, long zBb, long zBh, long zCb, long zCh)
{
  __shared__ __align__(16) short As[BM][BK + 4];
  __shared__ __align__(16) short Bs[BN][BK + 4];
  int z = blockIdx.z, zb = z / zH, zh = z % zH;
  long aoff = (long)zb * zAb + (long)zh * zAh;
  long boff = (long)zb * zBb + (long)zh * zBh;
  long coff = (long)zb * zCb + (long)zh * zCh;
  const float* Af = (const float*)Av + aoff;
  const short* Ah = (const short*)Av + aoff;
  const float* Bp = B + boff;
  int m0 = blockIdx.y * BM, n0 = blockIdx.x * BN;
  int tid = threadIdx.x, lane = tid & 63, wave = tid >> 6;
  int wm = (wave >> 1) * 64, wn = (wave & 1) * 64;
  f4v acc[4][4] = {};
  for (int k0 = 0; k0 < K; k0 += BK) {
    // stage A tile (BM x BK) -> bf16 LDS
    for (int i = tid; i < BM * BK; i += 256) {
      int r = i >> 5, c = i & 31;
      int gm = m0 + r, gk = k0 + c;
      short v = 0;
      if (gm < M && gk < K)
        v = A16 ? Ah[(long)gm * lda + gk] : f2bf(Af[(long)gm * lda + gk]);
      As[r][c] = v;
    }
    // stage B tile -> LDS transposed as [BN][BK]
    for (int i = tid; i < BN * BK; i += 256) {
      int kk, nn;
      if (BT) { nn = i >> 5; kk = i & 31; } else { kk = i >> 7; nn = i & 127; }
      int gk = k0 + kk, gn = n0 + nn;
      float v = 0.f;
      if (gk < K && gn < N)
        v = BT ? Bp[(long)gn * ldb + gk] : Bp[(long)gk * ldb + gn];
      Bs[nn][kk] = f2bf(v);
    }
    __syncthreads();
    int lr = lane & 15, lk = (lane >> 4) * 4;
    #pragma unroll
    for (int ks = 0; ks < 2; ++ks) {
      s4v af[4], bf[4];
      #pragma unroll
      for (int mi = 0; mi < 4; ++mi)
        af[mi] = *(const s4v*)&As[wm + mi * 16 + lr][ks * 16 + lk];
      #pragma unroll
      for (int ni = 0; ni < 4; ++ni)
        bf[ni] = *(const s4v*)&Bs[wn + ni * 16 + lr][ks * 16 + lk];
      #pragma unroll
      for (int mi = 0; mi < 4; ++mi)
        #pragma unroll
        for (int ni = 0; ni < 4; ++ni)
          acc[mi][ni] = __builtin_amdgcn_mfma_f32_16x16x16bf16_1k(
              af[mi], bf[ni], acc[mi][ni], 0, 0, 0);
    }
    __syncthreads();
  }
  float* Cf = (float*)Cv + coff;
  short* Cb = (short*)Cv + coff;
  #pragma unroll
  for (int mi = 0; mi < 4; ++mi)
    #pragma unroll
    for (int ni = 0; ni < 4; ++ni) {
      int col = n0 + wn + ni * 16 + (lane & 15);
      if (col >= N) continue;
      float bv = (flags & 1) ? bias[col] : 0.f;
      #pragma unroll
      for (int j = 0; j < 4; ++j) {
        int row = m0 + wm + mi * 16 + (lane >> 4) * 4 + j;
        if (row >= M) continue;
        float v = acc[mi][ni][j] + bv;
        if (flags & 2) v = 0.5f * v * (1.f + erff(v * 0.70710678118f));
        long ci = (long)row * ldc + col;
        if (flags & 8) {
          Cb[ci] = f2bf(v);
        } else {
          if (flags & 4) v += Cf[ci];
          Cf[ci] = v;
        }
      }
    }
}

// ---------------- LayerNorm over D=768, one block per row ----------------
__global__ __launch_bounds__(256) void ln_k(const float* __restrict__ x,
    const float* __restrict__ g, const float* __restrict__ b,
    float* __restrict__ y, int rows)
{
  int row = blockIdx.x;
  if (row >= rows) return;
  const float* xr = x + (long)row * 768;
  float* yr = y + (long)row * 768;
  int t = threadIdx.x;
  float v0 = xr[t], v1 = xr[t + 256], v2 = xr[t + 512];
  float s = v0 + v1 + v2, s2 = v0 * v0 + v1 * v1 + v2 * v2;
  #pragma unroll
  for (int o = 32; o > 0; o >>= 1) { s += __shfl_down(s, o); s2 += __shfl_down(s2, o); }
  __shared__ float as_[4], as2_[4];
  if ((t & 63) == 0) { as_[t >> 6] = s; as2_[t >> 6] = s2; }
  __syncthreads();
  s = as_[0] + as_[1] + as_[2] + as_[3];
  s2 = as2_[0] + as2_[1] + as2_[2] + as2_[3];
  float mean = s * (1.f / 768.f);
  float var = s2 * (1.f / 768.f) - mean * mean;
  float r = rsqrtf(var + 1e-5f);
  yr[t]       = (v0 - mean) * r * g[t]       + b[t];
  yr[t + 256] = (v1 - mean) * r * g[t + 256] + b[t + 256];
  yr[t + 512] = (v2 - mean) * r * g[t + 512] + b[t + 512];
}

// ---------------- row softmax over 1025 cols, bf16 in/out, in-place ----------------
__global__ __launch_bounds__(256) void softmax_k(short* __restrict__ S)
{
  long row = blockIdx.x;
  short* p = S + row * 1025;
  int t = threadIdx.x;
  float v[5];
  float mx = -3.4e38f;
  #pragma unroll
  for (int j = 0; j < 5; ++j) {
    int idx = t + j * 256;
    if (idx < 1025) { v[j] = bf2f(p[idx]) * 0.125f; mx = fmaxf(mx, v[j]); }
    else v[j] = -3.4e38f;
  }
  #pragma unroll
  for (int o = 32; o > 0; o >>= 1) mx = fmaxf(mx, __shfl_down(mx, o));
  __shared__ float red[4];
  if ((t & 63) == 0) red[t >> 6] = mx;
  __syncthreads();
  mx = fmaxf(fmaxf(red[0], red[1]), fmaxf(red[2], red[3]));
  float sum = 0.f;
  #pragma unroll
  for (int j = 0; j < 5; ++j) {
    int idx = t + j * 256;
    if (idx < 1025) { v[j] = __expf(v[j] - mx); sum += v[j]; }
  }
  #pragma unroll
  for (int o = 32; o > 0; o >>= 1) sum += __shfl_down(sum, o);
  __shared__ float red2[4];
  if ((t & 63) == 0) red2[t >> 6] = sum;
  __syncthreads();
  sum = red2[0] + red2[1] + red2[2] + red2[3];
  float inv = 1.f / sum;
  #pragma unroll
  for (int j = 0; j < 5; ++j) {
    int idx = t + j * 256;
    if (idx < 1025) p[idx] = f2bf(v[j] * inv);
  }
}

// ---------------- patch extraction: x[4,1,512,512] -> A[4096][256] ----------------
__global__ __launch_bounds__(256) void im2col_k(const float* __restrict__ x, float* __restrict__ A)
{
  int i = blockIdx.x * 256 + threadIdx.x;   // 4096*256 total
  int k = i & 255, row = i >> 8;
  int px = k & 15, py = k >> 4;
  int gx = row & 31, gy = (row >> 5) & 31, b = row >> 10;
  A[i] = x[((long)(b * 512) + gy * 16 + py) * 512 + gx * 16 + px];
}

// ---------------- t = concat(cls, tok) + pos ----------------
__global__ __launch_bounds__(256) void assemble_k(const float* __restrict__ tok,
    const float* __restrict__ cls, const float* __restrict__ pos, float* __restrict__ t)
{
  int i = blockIdx.x * 256 + threadIdx.x;   // 4100*768 total
  int d = i % 768; int rn = i / 768; int n = rn % 1025; int b = rn / 1025;
  float v = (n == 0) ? cls[d] : tok[((long)(b * 1024 + n - 1)) * 768 + d];
  t[i] = v + pos[n * 768 + d];
}

extern "C" void kernel_launch(void* const* d_in, const int* in_sizes, int n_in,
                              void* d_out, int out_size, void* d_ws, size_t ws_size,
                              hipStream_t stream)
{
  const float* x       = (const float*)d_in[0];
  const float* conv_w  = (const float*)d_in[1];
  const float* conv_b  = (const float*)d_in[2];
  const float* cls     = (const float*)d_in[3];
  const float* pos     = (const float*)d_in[4];
  const float* qkv_w   = (const float*)d_in[5];
  const float* merge_w = (const float*)d_in[6];
  const float* merge_b = (const float*)d_in[7];
  const float* ln1_s   = (const float*)d_in[8];
  const float* ln1_b   = (const float*)d_in[9];
  const float* ln2_s   = (const float*)d_in[10];
  const float* ln2_b   = (const float*)d_in[11];
  const float* ffn_w1  = (const float*)d_in[12];
  const float* ffn_b1  = (const float*)d_in[13];
  const float* ffn_w2  = (const float*)d_in[14];
  const float* ffn_b2  = (const float*)d_in[15];
  const float* lnf_s   = (const float*)d_in[16];
  const float* lnf_b   = (const float*)d_in[17];

  char* ws = (char*)d_ws;
  auto alignup = [](size_t v) { return (v + 255) & ~(size_t)255; };
  size_t off = 0;
  float* t   = (float*)(ws + off); off = alignup(off + 4100ul * 768 * 4);
  float* h   = (float*)(ws + off); off = alignup(off + 4100ul * 768 * 4);
  float* qkv = (float*)(ws + off); off = alignup(off + 4100ul * 1536 * 4);
  short* S   = (short*)(ws + off); off = alignup(off + 32ul * 1025 * 1025 * 2);
  float* O   = (float*)(ws + off); off = alignup(off + 4100ul * 512 * 4);
  float* f   = (float*)(ws + off); off = alignup(off + 4100ul * 2048 * 4);
  float* Apatch = h;   // alias (4 MB <= 12.6 MB, h not yet live)
  float* tok    = f;   // alias (12.6 MB <= 33.6 MB, f not yet live)

  dim3 blk(256);

  // ---- patch embed ----
  im2col_k<<<4096, blk, 0, stream>>>(x, Apatch);
  {
    dim3 g((768 + BN - 1) / BN, (4096 + BM - 1) / BM, 1);
    gemm_k<true, false><<<g, blk, 0, stream>>>(Apatch, conv_w, tok, conv_b,
        4096, 768, 256, 256, 256, 768, 1, 1, 0, 0, 0, 0, 0, 0);
  }
  assemble_k<<<12300, blk, 0, stream>>>(tok, cls, pos, t);

  for (int i = 0; i < 12; ++i) {
    // h = LN1(t)
    ln_k<<<4100, blk, 0, stream>>>(t, ln1_s + i * 768, ln1_b + i * 768, h, 4100);
    // qkv = h @ qkv_w[i]
    {
      dim3 g((1536 + 127) / 128, (4100 + 127) / 128, 1);
      gemm_k<false, false><<<g, blk, 0, stream>>>(h, qkv_w + (long)i * 768 * 1536, qkv, nullptr,
          4100, 1536, 768, 768, 1536, 1536, 0, 1, 0, 0, 0, 0, 0, 0);
    }
    // S[z] = Q K^T  (bf16 out), z = b*8+h
    {
      dim3 g((1025 + 127) / 128, (1025 + 127) / 128, 32);
      gemm_k<true, false><<<g, blk, 0, stream>>>(qkv, qkv + 64, S, nullptr,
          1025, 1025, 64, 1536, 1536, 1025, 8, 8,
          1025l * 1536, 192, 1025l * 1536, 192,
          8l * 1025 * 1025, 1025l * 1025);
    }
    // softmax rows (scale 1/8 inside)
    softmax_k<<<32 * 1025, blk, 0, stream>>>(S);
    // O[z] = P V
    {
      dim3 g(1, (1025 + 127) / 128, 32);
      gemm_k<false, true><<<g, blk, 0, stream>>>(S, qkv + 128, O, nullptr,
          1025, 64, 1025, 1025, 1536, 512, 0, 8,
          8l * 1025 * 1025, 1025l * 1025, 1025l * 1536, 192,
          1025l * 512, 64);
    }
    // t += O @ merge_w[i] + merge_b[i]
    {
      dim3 g((768 + 127) / 128, (4100 + 127) / 128, 1);
      gemm_k<false, false><<<g, blk, 0, stream>>>(O, merge_w + (long)i * 512 * 768, t,
          merge_b + i * 768, 4100, 768, 512, 512, 768, 768, 1 | 4, 1, 0, 0, 0, 0, 0, 0);
    }
    // h = LN2(t)
    ln_k<<<4100, blk, 0, stream>>>(t, ln2_s + i * 768, ln2_b + i * 768, h, 4100);
    // f = GELU(h @ ffn_w1[i] + b1)
    {
      dim3 g((2048 + 127) / 128, (4100 + 127) / 128, 1);
      gemm_k<false, false><<<g, blk, 0, stream>>>(h, ffn_w1 + (long)i * 768 * 2048, f,
          ffn_b1 + i * 2048, 4100, 2048, 768, 768, 2048, 2048, 1 | 2, 1, 0, 0, 0, 0, 0, 0);
    }
    // t += f @ ffn_w2[i] + b2
    {
      dim3 g((768 + 127) / 128, (4100 + 127) / 128, 1);
      gemm_k<false, false><<<g, blk, 0, stream>>>(f, ffn_w2 + (long)i * 2048 * 768, t,
          ffn_b2 + i * 768, 4100, 768, 2048, 2048, 768, 768, 1 | 4, 1, 0, 0, 0, 0, 0, 0);
    }
  }
  // final LN -> d_out
  ln_k<<<4100, blk, 0, stream>>>(t, lnf_s, lnf_b, (float*)d_out, 4100);
}

// Round 2
// 4621.661 us; speedup vs baseline: 5.0951x; 5.0951x over previous
//
#include <hip/hip_runtime.h>

#define DEV __device__ __forceinline__

typedef short s8v __attribute__((ext_vector_type(8)));
typedef float f4v __attribute__((ext_vector_type(4)));

DEV short f2bf(float f) {
  unsigned u = __float_as_uint(f);
  u += 0x7FFFu + ((u >> 16) & 1u);
  return (short)(u >> 16);
}
DEV float bf2f(short s) { return __uint_as_float(((unsigned)(unsigned short)s) << 16); }

DEV void gld_lds16(const short* g, short* l) {
  __builtin_amdgcn_global_load_lds(
      (const __attribute__((address_space(1))) void*)g,
      (__attribute__((address_space(3))) void*)l, 16, 0, 0);
}

// ---------------- bf16 BT GEMM: C[M,N] = A[M,K] @ B[N,K]^T ----------------
// A,B bf16 row-major with leading dims lda,ldb (elements, %8==0).
// flags: 1=+bias[col], 2=exact GELU, 4=accumulate into fp32 C, 8=bf16 output
// z-batching: z=(zb,zh), element offsets zb*z?b + zh*z?h
__global__ __launch_bounds__(256) void gemm_bt(
    const short* __restrict__ A, const short* __restrict__ B, void* __restrict__ Cv,
    const float* __restrict__ bias,
    int M, int N, int K, int lda, int ldb, int ldc, int flags, int zH,
    long zAb, long zAh, long zBb, long zBh, long zCb, long zCh)
{
  __shared__ __align__(16) short As[128][64];
  __shared__ __align__(16) short Bs[128][64];
  int z = blockIdx.z, zb = z / zH, zh = z - zb * zH;
  const short* Ap = A + zb * zAb + zh * zAh;
  const short* Bp = B + zb * zBb + zh * zBh;
  long coff = zb * zCb + zh * zCh;
  int m0 = blockIdx.y * 128, n0 = blockIdx.x * 128;
  int tid = threadIdx.x, lane = tid & 63, wave = tid >> 6;
  int wm = (wave >> 1) * 64, wn = (wave & 1) * 64;
  int lr = lane & 15, kg = lane >> 4;
  int srow = lane >> 3, sch = (lane & 7) * 8;
  f4v acc[4][4] = {};
  for (int k0 = 0; k0 < K; k0 += 64) {
    #pragma unroll
    for (int i = 0; i < 4; ++i) {
      int rt = wave * 32 + i * 8 + srow;             // tile row this lane stages
      gld_lds16(Ap + (long)(m0 + rt) * lda + k0 + sch, &As[0][0] + (wave * 4 + i) * 512);
      gld_lds16(Bp + (long)(n0 + rt) * ldb + k0 + sch, &Bs[0][0] + (wave * 4 + i) * 512);
    }
    __syncthreads();
    #pragma unroll
    for (int ks = 0; ks < 2; ++ks) {
      s8v av[4], bv[4];
      #pragma unroll
      for (int mi = 0; mi < 4; ++mi)
        av[mi] = *(const s8v*)&As[wm + mi * 16 + lr][ks * 32 + kg * 8];
      #pragma unroll
      for (int ni = 0; ni < 4; ++ni)
        bv[ni] = *(const s8v*)&Bs[wn + ni * 16 + lr][ks * 32 + kg * 8];
      #pragma unroll
      for (int mi = 0; mi < 4; ++mi)
        #pragma unroll
        for (int ni = 0; ni < 4; ++ni)
          acc[mi][ni] = __builtin_amdgcn_mfma_f32_16x16x32_bf16(av[mi], bv[ni], acc[mi][ni], 0, 0, 0);
    }
    __syncthreads();
  }
  float* Cf = (float*)Cv + coff;
  short* Cb = (short*)Cv + coff;
  #pragma unroll
  for (int mi = 0; mi < 4; ++mi)
    #pragma unroll
    for (int ni = 0; ni < 4; ++ni) {
      int col = n0 + wn + ni * 16 + lr;
      if (col >= N) continue;
      float bvv = (flags & 1) ? bias[col] : 0.f;
      #pragma unroll
      for (int j = 0; j < 4; ++j) {
        int row = m0 + wm + mi * 16 + kg * 4 + j;
        if (row >= M) continue;
        float v = acc[mi][ni][j] + bvv;
        if (flags & 2) v = 0.5f * v * (1.f + erff(v * 0.70710678118f));
        long ci = (long)row * ldc + col;
        if (flags & 8) Cb[ci] = f2bf(v);
        else { if (flags & 4) v += Cf[ci]; Cf[ci] = v; }
      }
    }
}

// ---------------- transpose+convert: w[K][N] fp32 -> wt[N][K] bf16 ----------------
__global__ __launch_bounds__(256) void tconv_k(const float* __restrict__ w,
    short* __restrict__ wt, int K, int N)
{
  __shared__ float tile[32][33];
  int n0 = blockIdx.x * 32, k0 = blockIdx.y * 32;
  int tx = threadIdx.x & 31, ty = threadIdx.x >> 5;   // 8 rows/pass
  #pragma unroll
  for (int j = 0; j < 4; ++j)
    tile[ty + j * 8][tx] = w[(long)(k0 + ty + j * 8) * N + n0 + tx];
  __syncthreads();
  #pragma unroll
  for (int j = 0; j < 4; ++j)
    wt[(long)(n0 + ty + j * 8) * K + k0 + tx] = f2bf(tile[tx][ty + j * 8]);
}

// ---------------- elementwise fp32 -> bf16 ----------------
__global__ __launch_bounds__(256) void cvt_k(const float* __restrict__ in,
    short* __restrict__ out, int n)
{
  int i = blockIdx.x * 256 + threadIdx.x;
  if (i < n) out[i] = f2bf(in[i]);
}

// ---------------- LayerNorm D=768, one block per row ----------------
DEV void st_ln(float* p, float v) { *p = v; }
DEV void st_ln(short* p, float v) { *p = f2bf(v); }

template<typename OT>
__global__ __launch_bounds__(256) void ln_k(const float* __restrict__ x,
    const float* __restrict__ g, const float* __restrict__ b,
    OT* __restrict__ y, int rows)
{
  int row = blockIdx.x;
  if (row >= rows) return;
  const float* xr = x + (long)row * 768;
  OT* yr = y + (long)row * 768;
  int t = threadIdx.x;
  float v0 = xr[t], v1 = xr[t + 256], v2 = xr[t + 512];
  float s = v0 + v1 + v2, s2 = v0 * v0 + v1 * v1 + v2 * v2;
  #pragma unroll
  for (int o = 32; o > 0; o >>= 1) { s += __shfl_down(s, o); s2 += __shfl_down(s2, o); }
  __shared__ float as_[4], as2_[4];
  if ((t & 63) == 0) { as_[t >> 6] = s; as2_[t >> 6] = s2; }
  __syncthreads();
  s = as_[0] + as_[1] + as_[2] + as_[3];
  s2 = as2_[0] + as2_[1] + as2_[2] + as2_[3];
  float mean = s * (1.f / 768.f);
  float var = s2 * (1.f / 768.f) - mean * mean;
  float r = rsqrtf(var + 1e-5f);
  st_ln(&yr[t],       (v0 - mean) * r * g[t]       + b[t]);
  st_ln(&yr[t + 256], (v1 - mean) * r * g[t + 256] + b[t + 256]);
  st_ln(&yr[t + 512], (v2 - mean) * r * g[t + 512] + b[t + 512]);
}

// ---------------- softmax over row of 1025 scores (ld 1088), zero pad cols ----------------
__global__ __launch_bounds__(256) void softmax_k(short* __restrict__ S)
{
  int zt = blockIdx.y, r = blockIdx.x;
  short* p = S + ((long)zt * 1025 + r) * 1088;
  int t = threadIdx.x;
  float v[5];
  float mx = -3.4e38f;
  #pragma unroll
  for (int j = 0; j < 5; ++j) {
    int idx = t + j * 256;
    if (idx < 1025) { v[j] = bf2f(p[idx]) * 0.125f; mx = fmaxf(mx, v[j]); }
    else v[j] = -3.4e38f;
  }
  #pragma unroll
  for (int o = 32; o > 0; o >>= 1) mx = fmaxf(mx, __shfl_down(mx, o));
  __shared__ float red[4];
  if ((t & 63) == 0) red[t >> 6] = mx;
  __syncthreads();
  mx = fmaxf(fmaxf(red[0], red[1]), fmaxf(red[2], red[3]));
  float sum = 0.f;
  #pragma unroll
  for (int j = 0; j < 5; ++j) {
    int idx = t + j * 256;
    if (idx < 1025) { v[j] = __expf(v[j] - mx); sum += v[j]; }
  }
  #pragma unroll
  for (int o = 32; o > 0; o >>= 1) sum += __shfl_down(sum, o);
  __shared__ float red2[4];
  if ((t & 63) == 0) red2[t >> 6] = sum;
  __syncthreads();
  sum = red2[0] + red2[1] + red2[2] + red2[3];
  float inv = 1.f / sum;
  #pragma unroll
  for (int j = 0; j < 5; ++j) {
    int idx = t + j * 256;
    if (idx < 1025) p[idx] = f2bf(v[j] * inv);
    else if (idx < 1088) p[idx] = 0;
  }
}

// ---------------- V transpose: qkv V-slice -> Vt[z][64][1088] (pad cols zero) ----------------
__global__ __launch_bounds__(256) void vtrans_k(const short* __restrict__ qkv,
    short* __restrict__ Vt)
{
  int z = blockIdx.y, zb = z >> 3, zh = z & 7;
  int n0 = blockIdx.x * 64;
  __shared__ short tile[64][65];
  const short* src = qkv + (long)zb * 1025 * 1536 + zh * 192 + 128;
  #pragma unroll
  for (int pass = 0; pass < 16; ++pass) {
    int idx = pass * 256 + threadIdx.x;
    int dd = idx & 63, nn = idx >> 6;
    int n = n0 + nn;
    tile[dd][nn] = (n < 1025) ? src[(long)n * 1536 + dd] : (short)0;
  }
  __syncthreads();
  short* dst = Vt + (long)z * 64 * 1088;
  #pragma unroll
  for (int pass = 0; pass < 16; ++pass) {
    int idx = pass * 256 + threadIdx.x;
    int nn = idx & 63, dd = idx >> 6;
    dst[(long)dd * 1088 + n0 + nn] = tile[dd][nn];
  }
}

// ---------------- patch extraction: x[4,1,512,512] -> A[4096][256] bf16 ----------------
__global__ __launch_bounds__(256) void im2col_k(const float* __restrict__ x,
    short* __restrict__ A)
{
  int i = blockIdx.x * 256 + threadIdx.x;
  int k = i & 255, row = i >> 8;
  int px = k & 15, py = k >> 4;
  int gx = row & 31, gy = (row >> 5) & 31, b = row >> 10;
  A[i] = f2bf(x[((long)(b * 512) + gy * 16 + py) * 512 + gx * 16 + px]);
}

// ---------------- t = concat(cls, tok) + pos  (tok bf16, t fp32) ----------------
__global__ __launch_bounds__(256) void assemble_k(const short* __restrict__ tok,
    const float* __restrict__ cls, const float* __restrict__ pos, float* __restrict__ t)
{
  int i = blockIdx.x * 256 + threadIdx.x;   // 4100*768
  int d = i % 768; int rn = i / 768; int n = rn % 1025; int b = rn / 1025;
  float v = (n == 0) ? cls[d] : bf2f(tok[((long)(b * 1024 + n - 1)) * 768 + d]);
  t[i] = v + pos[n * 768 + d];
}

extern "C" void kernel_launch(void* const* d_in, const int* in_sizes, int n_in,
                              void* d_out, int out_size, void* d_ws, size_t ws_size,
                              hipStream_t stream)
{
  const float* x       = (const float*)d_in[0];
  const float* conv_w  = (const float*)d_in[1];
  const float* conv_b  = (const float*)d_in[2];
  const float* cls     = (const float*)d_in[3];
  const float* pos     = (const float*)d_in[4];
  const float* qkv_w   = (const float*)d_in[5];
  const float* merge_w = (const float*)d_in[6];
  const float* merge_b = (const float*)d_in[7];
  const float* ln1_s   = (const float*)d_in[8];
  const float* ln1_b   = (const float*)d_in[9];
  const float* ln2_s   = (const float*)d_in[10];
  const float* ln2_b   = (const float*)d_in[11];
  const float* ffn_w1  = (const float*)d_in[12];
  const float* ffn_b1  = (const float*)d_in[13];
  const float* ffn_w2  = (const float*)d_in[14];
  const float* ffn_b2  = (const float*)d_in[15];
  const float* lnf_s   = (const float*)d_in[16];
  const float* lnf_b   = (const float*)d_in[17];

  char* wsp = (char*)d_ws;
  size_t o = 0;
  auto take = [&](size_t bytes) { char* r = wsp + o; o = (o + bytes + 255) & ~(size_t)255; return r; };
  short* wq   = (short*)take(1536ul * 768 * 2);
  short* wm   = (short*)take(768ul * 512 * 2);
  short* wf1  = (short*)take(2048ul * 768 * 2);
  short* wf2  = (short*)take(768ul * 2048 * 2);
  short* wcv  = (short*)take(768ul * 256 * 2);
  float* t    = (float*)take(4100ul * 768 * 4);
  char*  hO   = take(4100ul * 768 * 2);              // h bf16 OR O bf16 [4][1025][512]
  short* qkv  = (short*)take(4ul * 1025 * 1536 * 2);
  short* S    = (short*)take(32ul * 1025 * 1088 * 2);
  char*  fV   = take(4100ul * 2048 * 2);             // f OR Vt OR (im2col + tok)
  take(1ul << 20);                                   // slack for tile over-reads

  short* h   = (short*)hO;
  short* O   = (short*)hO;
  short* f   = (short*)fV;
  short* Vt  = (short*)fV;
  short* imc = (short*)fV;
  short* tok = (short*)(fV + 4096ul * 256 * 2);

  dim3 blk(256);

  // ---- patch embed ----
  cvt_k<<<768, blk, 0, stream>>>(conv_w, wcv, 768 * 256);
  im2col_k<<<4096, blk, 0, stream>>>(x, imc);
  gemm_bt<<<dim3(6, 32, 1), blk, 0, stream>>>(imc, wcv, tok, conv_b,
      4096, 768, 256, 256, 256, 768, 1 | 8, 1, 0, 0, 0, 0, 0, 0);
  assemble_k<<<12300, blk, 0, stream>>>(tok, cls, pos, t);

  for (int i = 0; i < 12; ++i) {
    // weight prep (bf16 + transpose to [N][K])
    tconv_k<<<dim3(48, 24), blk, 0, stream>>>(qkv_w + (long)i * 768 * 1536, wq, 768, 1536);
    tconv_k<<<dim3(24, 16), blk, 0, stream>>>(merge_w + (long)i * 512 * 768, wm, 512, 768);
    tconv_k<<<dim3(64, 24), blk, 0, stream>>>(ffn_w1 + (long)i * 768 * 2048, wf1, 768, 2048);
    tconv_k<<<dim3(24, 64), blk, 0, stream>>>(ffn_w2 + (long)i * 2048 * 768, wf2, 2048, 768);

    // h = LN1(t)  (bf16)
    ln_k<short><<<4100, blk, 0, stream>>>(t, ln1_s + i * 768, ln1_b + i * 768, h, 4100);
    // qkv = h @ qkv_w  (bf16 out)
    gemm_bt<<<dim3(12, 33, 1), blk, 0, stream>>>(h, wq, qkv, nullptr,
        4100, 1536, 768, 768, 768, 1536, 8, 1, 0, 0, 0, 0, 0, 0);
    // Vt[z][d][n]
    vtrans_k<<<dim3(17, 32), blk, 0, stream>>>(qkv, Vt);
    // S = Q K^T (bf16, ld 1088)
    gemm_bt<<<dim3(9, 9, 32), blk, 0, stream>>>(qkv, qkv + 64, S, nullptr,
        1025, 1025, 64, 1536, 1536, 1088, 8, 8,
        1025l * 1536, 192, 1025l * 1536, 192,
        8l * 1025 * 1088, 1025l * 1088);
    // softmax (scale 1/8 inside, zero pad cols)
    softmax_k<<<dim3(1025, 32), blk, 0, stream>>>(S);
    // O = P V   (P: [1025][1088], Vt: [64][1088])
    gemm_bt<<<dim3(1, 9, 32), blk, 0, stream>>>(S, Vt, O, nullptr,
        1025, 64, 1088, 1088, 1088, 512, 8, 8,
        8l * 1025 * 1088, 1025l * 1088, 8l * 64 * 1088, 64l * 1088,
        1025l * 512, 64);
    // t += O @ merge_w + merge_b
    gemm_bt<<<dim3(6, 33, 1), blk, 0, stream>>>(O, wm, t, merge_b + i * 768,
        4100, 768, 512, 512, 512, 768, 1 | 4, 1, 0, 0, 0, 0, 0, 0);
    // h = LN2(t)
    ln_k<short><<<4100, blk, 0, stream>>>(t, ln2_s + i * 768, ln2_b + i * 768, h, 4100);
    // f = GELU(h @ ffn_w1 + b1)  (bf16)
    gemm_bt<<<dim3(16, 33, 1), blk, 0, stream>>>(h, wf1, f, ffn_b1 + i * 2048,
        4100, 2048, 768, 768, 768, 2048, 1 | 2 | 8, 1, 0, 0, 0, 0, 0, 0);
    // t += f @ ffn_w2 + b2
    gemm_bt<<<dim3(6, 33, 1), blk, 0, stream>>>(f, wf2, t, ffn_b2 + i * 768,
        4100, 768, 2048, 2048, 2048, 768, 1 | 4, 1, 0, 0, 0, 0, 0, 0);
  }
  // final LN -> d_out (fp32)
  ln_k<float><<<4100, blk, 0, stream>>>(t, lnf_s, lnf_b, (float*)d_out, 4100);
}

// Round 3
// 3381.273 us; speedup vs baseline: 6.9642x; 1.3668x over previous
//
#include <hip/hip_runtime.h>

#define DEV __device__ __forceinline__

typedef short s8v __attribute__((ext_vector_type(8)));
typedef float f4v __attribute__((ext_vector_type(4)));

DEV short f2bf(float f) {
  unsigned u = __float_as_uint(f);
  u += 0x7FFFu + ((u >> 16) & 1u);
  return (short)(u >> 16);
}
DEV float bf2f(short s) { return __uint_as_float(((unsigned)(unsigned short)s) << 16); }

DEV void gld_lds16(const short* g, short* l) {
  __builtin_amdgcn_global_load_lds(
      (const __attribute__((address_space(1))) void*)g,
      (__attribute__((address_space(3))) void*)l, 16, 0, 0);
}

// XCD-bijective swizzle (m204): consecutive output ids land on one XCD
DEV int xcd_swz(int id, int nwg) {
  int q8 = nwg >> 3, r8 = nwg & 7, xcd = id & 7, off = id >> 3;
  return (xcd < r8) ? (xcd * (q8 + 1) + off) : (r8 * (q8 + 1) + (xcd - r8) * q8 + off);
}

// ---------------- bf16 BT GEMM: C[M,N] = A[M,K] @ B[N,K]^T ----------------
// flags: 1=+bias[col], 2=exact GELU, 4=accumulate into fp32 C, 8=bf16 output
__global__ __launch_bounds__(256) void gemm_bt(
    const short* __restrict__ A, const short* __restrict__ B, void* __restrict__ Cv,
    const float* __restrict__ bias,
    int M, int N, int K, int lda, int ldb, int ldc, int flags, int zH,
    long zAb, long zAh, long zBb, long zBh, long zCb, long zCh)
{
  __shared__ __align__(16) short As[128][64];
  __shared__ __align__(16) short Bs[128][64];
  int z = blockIdx.z, zb = z / zH, zh = z - zb * zH;
  const short* Ap = A + zb * zAb + zh * zAh;
  const short* Bp = B + zb * zBb + zh * zBh;
  long coff = zb * zCb + zh * zCh;
  int nwg = gridDim.x * gridDim.y;
  int idl = blockIdx.y * gridDim.x + blockIdx.x;
  int swz = xcd_swz(idl, nwg);
  int bx = swz % gridDim.x, by = swz / gridDim.x;
  int m0 = by * 128, n0 = bx * 128;
  int tid = threadIdx.x, lane = tid & 63, wave = tid >> 6;
  int wm = (wave >> 1) * 64, wn = (wave & 1) * 64;
  int lr = lane & 15, kg = lane >> 4;
  int srow = lane >> 3, sch = (lane & 7) * 8;
  f4v acc[4][4] = {};
  for (int k0 = 0; k0 < K; k0 += 64) {
    #pragma unroll
    for (int i = 0; i < 4; ++i) {
      int rt = wave * 32 + i * 8 + srow;
      gld_lds16(Ap + (long)(m0 + rt) * lda + k0 + sch, &As[0][0] + (wave * 4 + i) * 512);
      gld_lds16(Bp + (long)(n0 + rt) * ldb + k0 + sch, &Bs[0][0] + (wave * 4 + i) * 512);
    }
    __syncthreads();
    #pragma unroll
    for (int ks = 0; ks < 2; ++ks) {
      s8v av[4], bv[4];
      #pragma unroll
      for (int mi = 0; mi < 4; ++mi)
        av[mi] = *(const s8v*)&As[wm + mi * 16 + lr][ks * 32 + kg * 8];
      #pragma unroll
      for (int ni = 0; ni < 4; ++ni)
        bv[ni] = *(const s8v*)&Bs[wn + ni * 16 + lr][ks * 32 + kg * 8];
      #pragma unroll
      for (int mi = 0; mi < 4; ++mi)
        #pragma unroll
        for (int ni = 0; ni < 4; ++ni)
          acc[mi][ni] = __builtin_amdgcn_mfma_f32_16x16x32_bf16(av[mi], bv[ni], acc[mi][ni], 0, 0, 0);
    }
    __syncthreads();
  }
  float* Cf = (float*)Cv + coff;
  short* Cb = (short*)Cv + coff;
  #pragma unroll
  for (int mi = 0; mi < 4; ++mi)
    #pragma unroll
    for (int ni = 0; ni < 4; ++ni) {
      int col = n0 + wn + ni * 16 + lr;
      if (col >= N) continue;
      float bvv = (flags & 1) ? bias[col] : 0.f;
      #pragma unroll
      for (int j = 0; j < 4; ++j) {
        int row = m0 + wm + mi * 16 + kg * 4 + j;
        if (row >= M) continue;
        float v = acc[mi][ni][j] + bvv;
        if (flags & 2) v = 0.5f * v * (1.f + erff(v * 0.70710678118f));
        long ci = (long)row * ldc + col;
        if (flags & 8) Cb[ci] = f2bf(v);
        else { if (flags & 4) v += Cf[ci]; Cf[ci] = v; }
      }
    }
}

// ---------------- fused flash attention ----------------
// qkv: [4][1025][1536] bf16 (Q at +0, K at +64, V at +128 per head zh*192)
// O:   [4][1025][512]  bf16 (col = zh*64 + d)
// grid: 544 = 17 qtiles * 32 z ; block 256 = 4 waves * 16 q-rows
__global__ __launch_bounds__(256) void flash_k(
    const short* __restrict__ qkv, short* __restrict__ O)
{
  int swz = xcd_swz(blockIdx.x, 544);
  int z = swz / 17, qt = swz - z * 17;
  int zb = z >> 3, zh = z & 7;
  const short* base = qkv + (long)zb * 1025 * 1536 + zh * 192;
  const short* Qg = base;
  const short* Kg = base + 64;
  const short* Vg = base + 128;
  int q0 = qt * 64;
  int tid = threadIdx.x, lane = tid & 63, w = tid >> 6;
  int lr = lane & 15, kg = lane >> 4;

  __shared__ __align__(16) short Qs[64][72];
  __shared__ __align__(16) short Ks[64 * 64];       // chunk-swizzled
  __shared__ __align__(16) short Vt[64][72];        // [d][key]
  __shared__ __align__(16) short Ps[4][16][72];     // per-wave P

  // stage Q (bounds-checked, zero-fill)
  for (int s = tid; s < 512; s += 256) {
    int row = s >> 3, ch = s & 7;
    s8v v = {};
    if (q0 + row < 1025) v = *(const s8v*)(Qg + (long)(q0 + row) * 1536 + ch * 8);
    *(s8v*)&Qs[row][ch * 8] = v;
  }
  __syncthreads();
  s8v aq[2];
  aq[0] = *(const s8v*)&Qs[w * 16 + lr][kg * 8];
  aq[1] = *(const s8v*)&Qs[w * 16 + lr][32 + kg * 8];

  f4v acc[4] = {};
  float m_run[4], l_run[4];
  #pragma unroll
  for (int j = 0; j < 4; ++j) { m_run[j] = -3.0e38f; l_run[j] = 0.f; }

  for (int kt = 0; kt < 17; ++kt) {
    int kv0 = kt * 64;
    __syncthreads();   // protect Ks/Vt overwrite vs prev-iter readers
    // stage K via global_load_lds; slot (row,c) holds K[row][(c^(row&7))*8..]
    {
      int s0 = w * 128;
      #pragma unroll
      for (int i = 0; i < 2; ++i) {
        int s = s0 + i * 64 + lane;
        int row = s >> 3, c = s & 7;
        int cg = c ^ (row & 7);
        gld_lds16(Kg + (long)(kv0 + row) * 1536 + cg * 8, Ks + (s0 + i * 64) * 8);
      }
    }
    // stage V transposed (bounds-checked zero-fill; conflict-free LDS writes)
    #pragma unroll
    for (int p = 0; p < 2; ++p) {
      int s = p * 256 + tid;
      int key = s & 63, ch = s >> 6;
      s8v v = {};
      if (kv0 + key < 1025) v = *(const s8v*)(Vg + (long)(kv0 + key) * 1536 + ch * 8);
      #pragma unroll
      for (int j = 0; j < 8; ++j) Vt[ch * 8 + j][key] = v[j];
    }
    __syncthreads();

    // S = Q K^T (swizzled K reads: 2-way banks)
    f4v sa[4] = {};
    #pragma unroll
    for (int ni = 0; ni < 4; ++ni) {
      int row = ni * 16 + lr;
      #pragma unroll
      for (int ks = 0; ks < 2; ++ks) {
        int c = (ks * 4 + kg) ^ (row & 7);
        s8v bk = *(const s8v*)(Ks + row * 64 + c * 8);
        sa[ni] = __builtin_amdgcn_mfma_f32_16x16x32_bf16(aq[ks], bk, sa[ni], 0, 0, 0);
      }
    }
    // mask + online softmax (rows = kg*4+j, cols = ni*16+lr)
    float sv[4][4], pv[4][4], tm[4], ts[4];
    #pragma unroll
    for (int j = 0; j < 4; ++j) tm[j] = -3.0e38f;
    #pragma unroll
    for (int ni = 0; ni < 4; ++ni) {
      bool valid = (kv0 + ni * 16 + lr) < 1025;
      #pragma unroll
      for (int j = 0; j < 4; ++j) {
        float s = valid ? sa[ni][j] * 0.125f : -3.0e38f;
        sv[ni][j] = s;
        tm[j] = fmaxf(tm[j], s);
      }
    }
    #pragma unroll
    for (int o = 1; o < 16; o <<= 1)
      #pragma unroll
      for (int j = 0; j < 4; ++j) tm[j] = fmaxf(tm[j], __shfl_xor(tm[j], o));
    float scale[4], m_new[4];
    #pragma unroll
    for (int j = 0; j < 4; ++j) {
      m_new[j] = fmaxf(m_run[j], tm[j]);
      scale[j] = __expf(m_run[j] - m_new[j]);
      m_run[j] = m_new[j];
      ts[j] = 0.f;
    }
    #pragma unroll
    for (int ni = 0; ni < 4; ++ni)
      #pragma unroll
      for (int j = 0; j < 4; ++j) {
        float p = __expf(sv[ni][j] - m_new[j]);
        pv[ni][j] = p;
        ts[j] += p;
      }
    #pragma unroll
    for (int o = 1; o < 16; o <<= 1)
      #pragma unroll
      for (int j = 0; j < 4; ++j) ts[j] += __shfl_xor(ts[j], o);
    #pragma unroll
    for (int j = 0; j < 4; ++j) l_run[j] = l_run[j] * scale[j] + ts[j];
    #pragma unroll
    for (int ni = 0; ni < 4; ++ni)
      #pragma unroll
      for (int j = 0; j < 4; ++j) acc[ni][j] *= scale[j];
    // P -> per-wave LDS (C-layout -> A-layout via explicit coords)
    #pragma unroll
    for (int ni = 0; ni < 4; ++ni)
      #pragma unroll
      for (int j = 0; j < 4; ++j)
        Ps[w][kg * 4 + j][ni * 16 + lr] = f2bf(pv[ni][j]);
    asm volatile("s_waitcnt lgkmcnt(0)" ::: "memory");
    // O += P V
    s8v ap[2];
    ap[0] = *(const s8v*)&Ps[w][lr][kg * 8];
    ap[1] = *(const s8v*)&Ps[w][lr][32 + kg * 8];
    #pragma unroll
    for (int ni = 0; ni < 4; ++ni) {
      #pragma unroll
      for (int ks = 0; ks < 2; ++ks) {
        s8v bvv = *(const s8v*)&Vt[ni * 16 + lr][ks * 32 + kg * 8];
        acc[ni] = __builtin_amdgcn_mfma_f32_16x16x32_bf16(ap[ks], bvv, acc[ni], 0, 0, 0);
      }
    }
  }
  // epilogue: normalize + write
  float inv[4];
  #pragma unroll
  for (int j = 0; j < 4; ++j) inv[j] = 1.f / l_run[j];
  #pragma unroll
  for (int ni = 0; ni < 4; ++ni)
    #pragma unroll
    for (int j = 0; j < 4; ++j) {
      int row = q0 + w * 16 + kg * 4 + j;
      if (row < 1025)
        O[((long)(zb * 1025 + row)) * 512 + zh * 64 + ni * 16 + lr] = f2bf(acc[ni][j] * inv[j]);
    }
}

// ---------------- transpose+convert: w[K][N] fp32 -> wt[N][K] bf16 ----------------
__global__ __launch_bounds__(256) void tconv_k(const float* __restrict__ w,
    short* __restrict__ wt, int K, int N)
{
  __shared__ float tile[32][33];
  int n0 = blockIdx.x * 32, k0 = blockIdx.y * 32;
  int tx = threadIdx.x & 31, ty = threadIdx.x >> 5;
  #pragma unroll
  for (int j = 0; j < 4; ++j)
    tile[ty + j * 8][tx] = w[(long)(k0 + ty + j * 8) * N + n0 + tx];
  __syncthreads();
  #pragma unroll
  for (int j = 0; j < 4; ++j)
    wt[(long)(n0 + ty + j * 8) * K + k0 + tx] = f2bf(tile[tx][ty + j * 8]);
}

// ---------------- elementwise fp32 -> bf16 ----------------
__global__ __launch_bounds__(256) void cvt_k(const float* __restrict__ in,
    short* __restrict__ out, int n)
{
  int i = blockIdx.x * 256 + threadIdx.x;
  if (i < n) out[i] = f2bf(in[i]);
}

// ---------------- LayerNorm D=768 ----------------
DEV void st_ln(float* p, float v) { *p = v; }
DEV void st_ln(short* p, float v) { *p = f2bf(v); }

template<typename OT>
__global__ __launch_bounds__(256) void ln_k(const float* __restrict__ x,
    const float* __restrict__ g, const float* __restrict__ b,
    OT* __restrict__ y, int rows)
{
  int row = blockIdx.x;
  if (row >= rows) return;
  const float* xr = x + (long)row * 768;
  OT* yr = y + (long)row * 768;
  int t = threadIdx.x;
  float v0 = xr[t], v1 = xr[t + 256], v2 = xr[t + 512];
  float s = v0 + v1 + v2, s2 = v0 * v0 + v1 * v1 + v2 * v2;
  #pragma unroll
  for (int o = 32; o > 0; o >>= 1) { s += __shfl_down(s, o); s2 += __shfl_down(s2, o); }
  __shared__ float as_[4], as2_[4];
  if ((t & 63) == 0) { as_[t >> 6] = s; as2_[t >> 6] = s2; }
  __syncthreads();
  s = as_[0] + as_[1] + as_[2] + as_[3];
  s2 = as2_[0] + as2_[1] + as2_[2] + as2_[3];
  float mean = s * (1.f / 768.f);
  float var = s2 * (1.f / 768.f) - mean * mean;
  float r = rsqrtf(var + 1e-5f);
  st_ln(&yr[t],       (v0 - mean) * r * g[t]       + b[t]);
  st_ln(&yr[t + 256], (v1 - mean) * r * g[t + 256] + b[t + 256]);
  st_ln(&yr[t + 512], (v2 - mean) * r * g[t + 512] + b[t + 512]);
}

// ---------------- patch extraction ----------------
__global__ __launch_bounds__(256) void im2col_k(const float* __restrict__ x,
    short* __restrict__ A)
{
  int i = blockIdx.x * 256 + threadIdx.x;
  int k = i & 255, row = i >> 8;
  int px = k & 15, py = k >> 4;
  int gx = row & 31, gy = (row >> 5) & 31, b = row >> 10;
  A[i] = f2bf(x[((long)(b * 512) + gy * 16 + py) * 512 + gx * 16 + px]);
}

// ---------------- t = concat(cls, tok) + pos ----------------
__global__ __launch_bounds__(256) void assemble_k(const short* __restrict__ tok,
    const float* __restrict__ cls, const float* __restrict__ pos, float* __restrict__ t)
{
  int i = blockIdx.x * 256 + threadIdx.x;
  int d = i % 768; int rn = i / 768; int n = rn % 1025; int b = rn / 1025;
  float v = (n == 0) ? cls[d] : bf2f(tok[((long)(b * 1024 + n - 1)) * 768 + d]);
  t[i] = v + pos[n * 768 + d];
}

extern "C" void kernel_launch(void* const* d_in, const int* in_sizes, int n_in,
                              void* d_out, int out_size, void* d_ws, size_t ws_size,
                              hipStream_t stream)
{
  const float* x       = (const float*)d_in[0];
  const float* conv_w  = (const float*)d_in[1];
  const float* conv_b  = (const float*)d_in[2];
  const float* cls     = (const float*)d_in[3];
  const float* pos     = (const float*)d_in[4];
  const float* qkv_w   = (const float*)d_in[5];
  const float* merge_w = (const float*)d_in[6];
  const float* merge_b = (const float*)d_in[7];
  const float* ln1_s   = (const float*)d_in[8];
  const float* ln1_b   = (const float*)d_in[9];
  const float* ln2_s   = (const float*)d_in[10];
  const float* ln2_b   = (const float*)d_in[11];
  const float* ffn_w1  = (const float*)d_in[12];
  const float* ffn_b1  = (const float*)d_in[13];
  const float* ffn_w2  = (const float*)d_in[14];
  const float* ffn_b2  = (const float*)d_in[15];
  const float* lnf_s   = (const float*)d_in[16];
  const float* lnf_b   = (const float*)d_in[17];

  char* wsp = (char*)d_ws;
  size_t o = 0;
  auto take = [&](size_t bytes) { char* r = wsp + o; o = (o + bytes + 255) & ~(size_t)255; return r; };
  short* wq   = (short*)take(1536ul * 768 * 2);
  short* wm   = (short*)take(768ul * 512 * 2);
  short* wf1  = (short*)take(2048ul * 768 * 2);
  short* wf2  = (short*)take(768ul * 2048 * 2);
  short* wcv  = (short*)take(768ul * 256 * 2);
  float* t    = (float*)take(4100ul * 768 * 4);
  char*  hO   = take(4100ul * 768 * 2);              // h bf16 OR O bf16 [4][1025][512]
  short* qkv  = (short*)take(4ul * 1025 * 1536 * 2);
  char*  fV   = take(4100ul * 2048 * 2);             // f OR (im2col + tok); also absorbs K-tail over-reads
  take(2ul << 20);                                   // slack for tile over-reads

  short* h   = (short*)hO;
  short* O   = (short*)hO;
  short* f   = (short*)fV;
  short* imc = (short*)fV;
  short* tok = (short*)(fV + 4096ul * 256 * 2);

  dim3 blk(256);

  // ---- patch embed ----
  cvt_k<<<768, blk, 0, stream>>>(conv_w, wcv, 768 * 256);
  im2col_k<<<4096, blk, 0, stream>>>(x, imc);
  gemm_bt<<<dim3(6, 32, 1), blk, 0, stream>>>(imc, wcv, tok, conv_b,
      4096, 768, 256, 256, 256, 768, 1 | 8, 1, 0, 0, 0, 0, 0, 0);
  assemble_k<<<12300, blk, 0, stream>>>(tok, cls, pos, t);

  for (int i = 0; i < 12; ++i) {
    tconv_k<<<dim3(48, 24), blk, 0, stream>>>(qkv_w + (long)i * 768 * 1536, wq, 768, 1536);
    tconv_k<<<dim3(24, 16), blk, 0, stream>>>(merge_w + (long)i * 512 * 768, wm, 512, 768);
    tconv_k<<<dim3(64, 24), blk, 0, stream>>>(ffn_w1 + (long)i * 768 * 2048, wf1, 768, 2048);
    tconv_k<<<dim3(24, 64), blk, 0, stream>>>(ffn_w2 + (long)i * 2048 * 768, wf2, 2048, 768);

    // h = LN1(t)
    ln_k<short><<<4100, blk, 0, stream>>>(t, ln1_s + i * 768, ln1_b + i * 768, h, 4100);
    // qkv = h @ qkv_w
    gemm_bt<<<dim3(12, 33, 1), blk, 0, stream>>>(h, wq, qkv, nullptr,
        4100, 1536, 768, 768, 768, 1536, 8, 1, 0, 0, 0, 0, 0, 0);
    // fused attention -> O
    flash_k<<<544, blk, 0, stream>>>(qkv, O);
    // t += O @ merge_w + merge_b
    gemm_bt<<<dim3(6, 33, 1), blk, 0, stream>>>(O, wm, t, merge_b + i * 768,
        4100, 768, 512, 512, 512, 768, 1 | 4, 1, 0, 0, 0, 0, 0, 0);
    // h = LN2(t)
    ln_k<short><<<4100, blk, 0, stream>>>(t, ln2_s + i * 768, ln2_b + i * 768, h, 4100);
    // f = GELU(h @ ffn_w1 + b1)
    gemm_bt<<<dim3(16, 33, 1), blk, 0, stream>>>(h, wf1, f, ffn_b1 + i * 2048,
        4100, 2048, 768, 768, 768, 2048, 1 | 2 | 8, 1, 0, 0, 0, 0, 0, 0);
    // t += f @ ffn_w2 + b2
    gemm_bt<<<dim3(6, 33, 1), blk, 0, stream>>>(f, wf2, t, ffn_b2 + i * 768,
        4100, 768, 2048, 2048, 2048, 768, 1 | 4, 1, 0, 0, 0, 0, 0, 0);
  }
  ln_k<float><<<4100, blk, 0, stream>>>(t, lnf_s, lnf_b, (float*)d_out, 4100);
}